// Round 9
// baseline (455.170 us; speedup 1.0000x reference)
//
#include <hip/hip_runtime.h>
#include <hip/hip_fp16.h>
#include <math.h>

#define NB1 10000
#define NB2 10000
#define DD  128
#define NV  4
#define B1P 10048            // desc1 rows padded to 64 (157 * 64)
#define B1R (B1P * NV)       // 40192 A-rows = 1256 row-groups of 32
#define NB2P 10112           // 316 row-groups of 32
#define NB2G 320             // B2c groups incl 4 slack (dead tail prefetch)
#define NJT 79               // j-tiles of 128
#define MB  256              // A-rows per block (64 desc1 rows)
#define BN  128
#define NCHUNK 6
#define SROWS 16
#define SCALE 64.0f          // pre-scale; acc = 4096*dot, epilogue applies -2/4096

typedef _Float16 f16x8 __attribute__((ext_vector_type(8)));
typedef __attribute__((ext_vector_type(16))) float f32x16;

__device__ __forceinline__ void gload_lds16(const void* g, void* l) {
    __builtin_amdgcn_global_load_lds(
        (const __attribute__((address_space(1))) void*)g,
        (__attribute__((address_space(3))) void*)l, 16, 0, 0);
}
__device__ __forceinline__ f32x16 mfma16(f16x8 a, f16x8 b, f32x16 c) {
    return __builtin_amdgcn_mfma_f32_32x32x16_f16(a, b, c, 0, 0, 0);
}
__device__ __forceinline__ void enc(float x, unsigned short* hb, unsigned short* lb) {
    float xs = SCALE * x;
    __half hh = __float2half_rn(xs);
    __half hl = __float2half_rn(xs - __half2float(hh));
    *hb = __half_as_ushort(hh);
    *lb = __half_as_ushort(hl);
}
// chunk-major map (ushort index): chunk = (rowgroup, col/16) of 512 ushort;
// within chunk: lane = (row&31) + bit3(col)*32, elem = col&7.  Lane-linear = MFMA fragment order.
__device__ __forceinline__ size_t cmap(int row, int col) {
    return ((size_t)(row >> 5) * 16 + (col >> 4)) * 512
         + (size_t)((row & 31) + (((col >> 3) & 1) << 5)) * 8 + (col & 7);
}

// ---------------- fused prep1 + steering chain (G transposed in LDS) ----------------

__global__ __launch_bounds__(128) void prep1s_kernel(
    const float* __restrict__ desc1, const float* __restrict__ G,
    unsigned short* __restrict__ A2c, float* __restrict__ n1) {
    __shared__ float GTl[128 * 129];   // GTl[c*129+f] = G[f][c]; pad 129 -> conflict-free
    __shared__ float src[SROWS][DD];
    __shared__ float p2[SROWS][2];
    const int t = threadIdx.x;        // 128
    const int i0 = blockIdx.x * SROWS;
    for (int f = 0; f < DD; ++f)
        GTl[t * 129 + f] = G[(size_t)f * DD + t];       // coalesced read; (t+f)%32 banks
    for (int r = 0; r < SROWS; ++r)
        src[r][t] = (i0 + r < NB1) ? desc1[(size_t)(i0 + r) * DD + t] : 0.f;
    __syncthreads();
    for (int k = 0; k < NV; ++k) {
        if (k > 0) {
            float out[SROWS];
#pragma unroll
            for (int r = 0; r < SROWS; ++r) out[r] = 0.f;
            for (int c = 0; c < DD; ++c) {
                float g = GTl[c * 129 + t];
#pragma unroll
                for (int r = 0; r < SROWS; ++r) out[r] = fmaf(src[r][c], g, out[r]);
            }
            __syncthreads();   // all reads of src done
#pragma unroll
            for (int r = 0; r < SROWS; ++r) src[r][t] = out[r];
            __syncthreads();
        }
        for (int r = 0; r < SROWS; ++r) {
            float x = src[r][t];
            unsigned short hb, lb;
            enc(x, &hb, &lb);
            int ar = (i0 + r) * NV + k;
            A2c[cmap(ar, t)] = hb;
            A2c[cmap(ar, 128 + t)] = lb;
            float s = x * x;
            for (int off = 32; off; off >>= 1) s += __shfl_down(s, off);
            if ((t & 63) == 0) p2[r][t >> 6] = s;
        }
        __syncthreads();
        if (t < SROWS) n1[(i0 + t) * NV + k] = p2[t][0] + p2[t][1];
        __syncthreads();
    }
}

__global__ void prep2_kernel(const float* __restrict__ desc2,
                             unsigned short* __restrict__ B2c, float* __restrict__ n2) {
    int j = blockIdx.x;           // 0..NB2P-1
    int t = threadIdx.x;          // 128
    float x = (j < NB2) ? desc2[j * DD + t] : 0.f;
    unsigned short hb, lb;
    enc(x, &hb, &lb);
    B2c[cmap(j, t)] = hb;
    B2c[cmap(j, 128 + t)] = lb;
    float s = x * x;
    for (int off = 32; off; off >>= 1) s += __shfl_down(s, off);
    __shared__ float p[2];
    if ((t & 63) == 0) p[t >> 6] = s;
    __syncthreads();
    if (t == 0) n2[j] = (j < NB2) ? (p[0] + p[1]) : 1e30f;
}

// ---------------- fused MFMA match kernel v3 ----------------
// 512 threads (8 waves: wm=w>>1 in 0..3 = 64-row quadrant, wn=w&1 = 64-col half).
// A fragments in VGPRs (128/wave), B in 4x8KB LDS ring, counted-vmcnt pipeline.
// Per phase: vmcnt(N); s_barrier; STAGE(p+3); compute(p).  vmcnt never 0 in loop.
// B-groups: g0=Bhi-kc0 x{aks0,aks2}, g1=Bhi-kc1 x{aks1,aks3}, g2=Blo-kc0 x{aks0}, g3=Blo-kc1 x{aks1}.

#define STAGE1(BSEL, J0V, C16B, HALF)                                             \
    {                                                                             \
        int k16h_ = w >> 2, nf_ = w & 3;                                          \
        size_t gc_ = (size_t)(((J0V) >> 5) + nf_) * 16 + (C16B) + (HALF) * 2 + k16h_; \
        gload_lds16((const char*)B2c + gc_ * 1024 + l * 16,                       \
                    LDSB + (BSEL) * 8192 + w * 1024 + l * 16);                    \
    }

#define COMP2(BSEL, HALF, AK0, AK1)                                               \
    {                                                                             \
        _Pragma("unroll")                                                         \
        for (int kh_ = 0; kh_ < 2; ++kh_) {                                       \
            f16x8 b0_ = *(const f16x8*)(LDSB + (BSEL) * 8192 + (kh_ * 4 + wn * 2 + 0) * 1024 + l * 16); \
            f16x8 b1_ = *(const f16x8*)(LDSB + (BSEL) * 8192 + (kh_ * 4 + wn * 2 + 1) * 1024 + l * 16); \
            acc[0][0] = mfma16(Areg[0][AK0][(HALF) * 2 + kh_], b0_, acc[0][0]);   \
            acc[0][1] = mfma16(Areg[0][AK0][(HALF) * 2 + kh_], b1_, acc[0][1]);   \
            acc[1][0] = mfma16(Areg[1][AK0][(HALF) * 2 + kh_], b0_, acc[1][0]);   \
            acc[1][1] = mfma16(Areg[1][AK0][(HALF) * 2 + kh_], b1_, acc[1][1]);   \
            acc[0][0] = mfma16(Areg[0][AK1][(HALF) * 2 + kh_], b0_, acc[0][0]);   \
            acc[0][1] = mfma16(Areg[0][AK1][(HALF) * 2 + kh_], b1_, acc[0][1]);   \
            acc[1][0] = mfma16(Areg[1][AK1][(HALF) * 2 + kh_], b0_, acc[1][0]);   \
            acc[1][1] = mfma16(Areg[1][AK1][(HALF) * 2 + kh_], b1_, acc[1][1]);   \
        }                                                                         \
    }

#define COMP1(BSEL, HALF, AK0)                                                    \
    {                                                                             \
        _Pragma("unroll")                                                         \
        for (int kh_ = 0; kh_ < 2; ++kh_) {                                       \
            f16x8 b0_ = *(const f16x8*)(LDSB + (BSEL) * 8192 + (kh_ * 4 + wn * 2 + 0) * 1024 + l * 16); \
            f16x8 b1_ = *(const f16x8*)(LDSB + (BSEL) * 8192 + (kh_ * 4 + wn * 2 + 1) * 1024 + l * 16); \
            acc[0][0] = mfma16(Areg[0][AK0][(HALF) * 2 + kh_], b0_, acc[0][0]);   \
            acc[0][1] = mfma16(Areg[0][AK0][(HALF) * 2 + kh_], b1_, acc[0][1]);   \
            acc[1][0] = mfma16(Areg[1][AK0][(HALF) * 2 + kh_], b0_, acc[1][0]);   \
            acc[1][1] = mfma16(Areg[1][AK0][(HALF) * 2 + kh_], b1_, acc[1][1]);   \
        }                                                                         \
    }

#define PH(VM, BS, J0S, C16S, HS, CMP)                           \
    asm volatile("s_waitcnt vmcnt(" VM ")" ::: "memory");        \
    __builtin_amdgcn_s_barrier();                                \
    __builtin_amdgcn_sched_barrier(0);                           \
    STAGE1(BS, J0S, C16S, HS);                                   \
    CMP

__global__ __launch_bounds__(512, 2) void match_kernel(
    const unsigned short* __restrict__ A2c, const unsigned short* __restrict__ B2c,
    const float* __restrict__ n1, const float* __restrict__ n2,
    float* __restrict__ pb, int* __restrict__ pj) {
    __shared__ __align__(16) char LDSB[4 * 8192];   // B ring
    __shared__ float LDSn1[256];
    const int t = threadIdx.x;
    const int l = t & 63, w = t >> 6;
    const int wm = w >> 1, wn = w & 1;
    const int c5 = l & 31, h = l >> 5;
    const int bi = blockIdx.x, ch = blockIdx.y;
    const int R0 = bi * MB;

    // ---- A fragments -> registers (coalesced 1KB wave-loads); oldest vmem ----
    f16x8 Areg[2][4][4];
#pragma unroll
    for (int a = 0; a < 2; ++a)
#pragma unroll
        for (int aks = 0; aks < 4; ++aks)
#pragma unroll
            for (int k16 = 0; k16 < 4; ++k16) {
                size_t g = (size_t)(bi * 8 + wm * 2 + a);
                Areg[a][aks][k16] = *(const f16x8*)(
                    (const char*)A2c + (g * 16 + aks * 4 + k16) * 1024 + l * 16);
            }
    // n1 -> LDS (uniform 1 vmem/thread; dup writes benign)
    { int idx = t & 255; LDSn1[idx] = n1[R0 + idx]; }

    const int jt0 = (ch * NJT) / NCHUNK;
    const int jt1 = ((ch + 1) * NJT) / NCHUNK;

    // prologue: 3 stage prefetches in flight
    STAGE1(0, jt0 * BN, 0, 0);   // q0 data
    STAGE1(1, jt0 * BN, 0, 1);   // q1 data
    STAGE1(2, jt0 * BN, 4, 0);   // q2 data
    asm volatile("s_waitcnt lgkmcnt(0)" ::: "memory");   // LDSn1 committed

    float best[2][4];
    int bj[2][4];
#pragma unroll
    for (int a = 0; a < 2; ++a)
#pragma unroll
        for (int rq = 0; rq < 4; ++rq) { best[a][rq] = 3.4e38f; bj[a][rq] = 0; }

    for (int jt = jt0; jt < jt1; ++jt) {
        const int j0 = jt * BN;
        // early n2 loads (used only in epilogue; pinned here by clobber asms)
        float nn0 = n2[j0 + wn * 64 + c5];
        float nn1 = n2[j0 + wn * 64 + 32 + c5];
        f32x16 acc[2][2];
#pragma unroll
        for (int a = 0; a < 2; ++a)
#pragma unroll
            for (int b = 0; b < 2; ++b)
#pragma unroll
                for (int e = 0; e < 16; ++e) acc[a][b][e] = 0.f;

        PH("4", 3, j0, 4, 1,       COMP2(0, 0, 0, 2));   // q0: comp g0.h0, stage q3
        PH("4", 0, j0, 8, 0,       COMP2(1, 1, 0, 2));   // q1: comp g0.h1, stage q4
        PH("4", 1, j0, 8, 1,       COMP2(2, 0, 1, 3));   // q2: comp g1.h0, stage q5
        PH("2", 2, j0, 12, 0,      COMP2(3, 1, 1, 3));   // q3: comp g1.h1, stage q6
        PH("2", 3, j0, 12, 1,      COMP1(0, 0, 0));      // q4: comp g2.h0, stage q7
        PH("2", 0, j0 + BN, 0, 0,  COMP1(1, 1, 0));      // q5: comp g2.h1, stage q0'
        PH("2", 1, j0 + BN, 0, 1,  COMP1(2, 0, 1));      // q6: comp g3.h0, stage q1'
        PH("2", 2, j0 + BN, 4, 0,  COMP1(3, 1, 1));      // q7: comp g3.h1, stage q2'

        // epilogue: e_m = n1_m - 2*dot (dot = acc/4096); min over versions; + n2; argmin
#pragma unroll
        for (int a = 0; a < 2; ++a)
#pragma unroll
            for (int b = 0; b < 2; ++b) {
                float nn = b ? nn1 : nn0;
                int j = j0 + wn * 64 + b * 32 + c5;
#pragma unroll
                for (int rq = 0; rq < 4; ++rq) {
                    float4 n1v = *(const float4*)&LDSn1[wm * 64 + a * 32 + 8 * rq + 4 * h];
                    float e0 = fmaf(-0.00048828125f, acc[a][b][4 * rq + 0], n1v.x);
                    float e1 = fmaf(-0.00048828125f, acc[a][b][4 * rq + 1], n1v.y);
                    float e2 = fmaf(-0.00048828125f, acc[a][b][4 * rq + 2], n1v.z);
                    float e3 = fmaf(-0.00048828125f, acc[a][b][4 * rq + 3], n1v.w);
                    float d = fminf(fminf(e0, e1), fminf(e2, e3)) + nn;
                    if (d < best[a][rq]) { best[a][rq] = d; bj[a][rq] = j; }
                }
            }
    }

    // reduce across the 32 column-lanes
#pragma unroll
    for (int off = 1; off < 32; off <<= 1) {
#pragma unroll
        for (int a = 0; a < 2; ++a)
#pragma unroll
            for (int rq = 0; rq < 4; ++rq) {
                float ov = __shfl_xor(best[a][rq], off);
                int oj = __shfl_xor(bj[a][rq], off);
                if (ov < best[a][rq] || (ov == best[a][rq] && oj < bj[a][rq])) {
                    best[a][rq] = ov; bj[a][rq] = oj;
                }
            }
    }
    if (c5 == 0) {
        int slot = ch * 2 + wn;
#pragma unroll
        for (int a = 0; a < 2; ++a)
#pragma unroll
            for (int rq = 0; rq < 4; ++rq) {
                int i = bi * 64 + wm * 16 + a * 8 + 2 * rq + h;
                pb[slot * B1P + i] = best[a][rq];
                pj[slot * B1P + i] = bj[a][rq];
            }
    }
}

__global__ void final_kernel(const float* __restrict__ pb, const int* __restrict__ pj,
                             float* __restrict__ out) {
    int i = blockIdx.x * 256 + threadIdx.x;
    if (i < NB1) {
        float bv = 3.4e38f;
        int bj = 0;
#pragma unroll
        for (int s = 0; s < 2 * NCHUNK; ++s) {
            float v = pb[s * B1P + i];
            int j = pj[s * B1P + i];
            if (v < bv || (v == bv && j < bj)) { bv = v; bj = j; }
        }
        out[i] = sqrtf(fmaxf(bv, 0.f));
        out[NB1 + 2 * i] = (float)i;
        out[NB1 + 2 * i + 1] = (float)bj;
    }
}

// ---------------- launch ----------------

extern "C" void kernel_launch(void* const* d_in, const int* in_sizes, int n_in,
                              void* d_out, int out_size, void* d_ws, size_t ws_size,
                              hipStream_t stream) {
    const float* desc1 = (const float*)d_in[0];
    const float* desc2 = (const float*)d_in[1];
    const float* G     = (const float*)d_in[2];

    unsigned short* A2c = (unsigned short*)d_ws;                 // 1256*16*512 ushort
    unsigned short* B2c = A2c + (size_t)(B1R / 32) * 16 * 512;   // NB2G*16*512 ushort
    float* n1 = (float*)(B2c + (size_t)NB2G * 16 * 512);         // B1R
    float* n2 = n1 + B1R;                                        // NB2P
    float* pb = n2 + NB2P;                                       // 2*NCHUNK*B1P
    int*   pj = (int*)(pb + 2 * NCHUNK * B1P);                   // 2*NCHUNK*B1P
    float* out = (float*)d_out;

    hipLaunchKernelGGL(prep1s_kernel, dim3(B1P / SROWS), dim3(128), 0, stream,
                       desc1, G, A2c, n1);
    hipLaunchKernelGGL(prep2_kernel, dim3(NB2P), dim3(128), 0, stream, desc2, B2c, n2);
    hipLaunchKernelGGL(match_kernel, dim3(B1R / MB, NCHUNK), dim3(512), 0, stream,
                       A2c, B2c, n1, n2, pb, pj);
    hipLaunchKernelGGL(final_kernel, dim3((NB1 + 255) / 256), dim3(256), 0, stream,
                       pb, pj, out);
}

// Round 10
// 400.371 us; speedup vs baseline: 1.1369x; 1.1369x over previous
//
#include <hip/hip_runtime.h>
#include <hip/hip_fp16.h>
#include <math.h>

#define NB1 10000
#define NB2 10000
#define DD  128
#define NV  4
#define B1P 10048            // desc1 rows padded (314 * 32)
#define B1R (B1P * NV)       // 40192 A-rows = 1256 rowgroups of 32
#define NB2P 10112           // 316 rowgroups
#define NB2G 320             // B2c rowgroups incl slack (dead tail prefetch)
#define NJT 79               // j-tiles of 128
#define MB  128              // A-rows per block (32 desc1 rows)
#define BN  128
#define NCHUNK 3
#define SCALE 64.0f          // pre-scale; acc = 4096*dot, epilogue applies -2/4096

typedef _Float16 f16x8 __attribute__((ext_vector_type(8)));
typedef __attribute__((ext_vector_type(16))) float f32x16;

__device__ __forceinline__ void gload_lds16(const void* g, void* l) {
    __builtin_amdgcn_global_load_lds(
        (const __attribute__((address_space(1))) void*)g,
        (__attribute__((address_space(3))) void*)l, 16, 0, 0);
}
__device__ __forceinline__ f32x16 mfma16(f16x8 a, f16x8 b, f32x16 c) {
    return __builtin_amdgcn_mfma_f32_32x32x16_f16(a, b, c, 0, 0, 0);
}
__device__ __forceinline__ void enc(float x, unsigned short* hb, unsigned short* lb) {
    float xs = SCALE * x;
    __half hh = __float2half_rn(xs);
    __half hl = __float2half_rn(xs - __half2float(hh));
    *hb = __half_as_ushort(hh);
    *lb = __half_as_ushort(hl);
}

// ---------------- prep ----------------

__global__ void gt_kernel(const float* __restrict__ G, float* __restrict__ GT) {
    int idx = blockIdx.x * 256 + threadIdx.x;
    if (idx < DD * DD) {
        int c = idx / DD, f = idx % DD;
        GT[idx] = G[f * DD + c];
    }
}

// 8 desc1 rows/block: 4-version chain + chunk-major pack + coalesced 1KB writes.
// chunk layout (per A-rowgroup of 32 rows): chunk c16 (16 of them), inside:
// lane = (row&31) + bit3(col)*32, elem = col&7  -> lane-linear = MFMA frag order.
__global__ __launch_bounds__(128) void prep1_kernel(
    const float* __restrict__ desc1, const float* __restrict__ GT,
    unsigned short* __restrict__ A2c, float* __restrict__ n1) {
    __shared__ float src[8][DD];                       // 4 KB
    __shared__ __align__(16) unsigned short cbuf[8192]; // 16 KB (one rowgroup, 16 chunks)
    __shared__ float p2[8][2];
    const int t = threadIdx.x;     // 128
    const int i0 = blockIdx.x * 8;
    for (int r = 0; r < 8; ++r)
        src[r][t] = (i0 + r < NB1) ? desc1[(size_t)(i0 + r) * DD + t] : 0.f;
    __syncthreads();
    for (int k = 0; k < NV; ++k) {
        float out[8];
        if (k == 0) {
#pragma unroll
            for (int r = 0; r < 8; ++r) out[r] = src[r][t];
        } else {
#pragma unroll
            for (int r = 0; r < 8; ++r) out[r] = 0.f;
            for (int c = 0; c < DD; ++c) {
                float g = GT[c * DD + t];
#pragma unroll
                for (int r = 0; r < 8; ++r) out[r] = fmaf(src[r][c], g, out[r]);
            }
            __syncthreads();
#pragma unroll
            for (int r = 0; r < 8; ++r) src[r][t] = out[r];
            __syncthreads();
        }
        const int c16h = t >> 4, half = (t >> 3) & 1, el = t & 7;
        for (int r = 0; r < 8; ++r) {
            unsigned short hb, lb;
            enc(out[r], &hb, &lb);
            int row32 = r * 4 + k;
            cbuf[c16h * 512 + (row32 + half * 32) * 8 + el] = hb;
            cbuf[(8 + c16h) * 512 + (row32 + half * 32) * 8 + el] = lb;
            float s = out[r] * out[r];
            for (int off = 32; off; off >>= 1) s += __shfl_down(s, off);
            if ((t & 63) == 0) p2[r][t >> 6] = s;
        }
        __syncthreads();
        if (t < 8) n1[(size_t)(i0 + t) * NV + k] = p2[t][0] + p2[t][1];
        __syncthreads();
    }
    // coalesced chunk write-out: 2 waves x 8 chunks
    const int wv = t >> 6, l = t & 63;
#pragma unroll
    for (int q = 0; q < 8; ++q) {
        int chunk = wv * 8 + q;
        int4 v = *(const int4*)((const char*)cbuf + chunk * 1024 + l * 16);
        *(int4*)((char*)A2c + ((size_t)blockIdx.x * 16 + chunk) * 1024 + l * 16) = v;
    }
}

// 32 desc2 rows/block: enc + chunk pack + coalesced writes + n2.
__global__ __launch_bounds__(256) void prep2_kernel(
    const float* __restrict__ desc2, unsigned short* __restrict__ B2c,
    float* __restrict__ n2) {
    __shared__ float srcf[32 * DD];                     // 16 KB
    __shared__ __align__(16) unsigned short cbuf[8192]; // 16 KB
    const int t = threadIdx.x;     // 256
    const int j0 = blockIdx.x * 32;
    for (int ii = 0; ii < 16; ++ii) {
        int idx = t + 256 * ii;
        int row = idx >> 7, col = idx & 127;
        srcf[idx] = (j0 + row < NB2) ? desc2[(size_t)(j0 + row) * DD + col] : 0.f;
    }
    __syncthreads();
    const int r = t >> 3, cg = t & 7;
    float s = 0.f;
#pragma unroll
    for (int e = 0; e < 16; ++e) {
        int c = cg * 16 + e;
        float x = srcf[r * DD + c];
        unsigned short hb, lb;
        enc(x, &hb, &lb);
        int lane = r + ((e >> 3) & 1) * 32;
        cbuf[cg * 512 + lane * 8 + (e & 7)] = hb;
        cbuf[(8 + cg) * 512 + lane * 8 + (e & 7)] = lb;
        s += x * x;
    }
    s += __shfl_xor(s, 1); s += __shfl_xor(s, 2); s += __shfl_xor(s, 4);
    if ((t & 7) == 0) n2[j0 + r] = (j0 + r < NB2) ? s : 1e30f;
    __syncthreads();
    const int wv = t >> 6, l = t & 63;
#pragma unroll
    for (int q = 0; q < 4; ++q) {
        int chunk = wv * 4 + q;
        int4 v = *(const int4*)((const char*)cbuf + chunk * 1024 + l * 16);
        *(int4*)((char*)B2c + ((size_t)blockIdx.x * 16 + chunk) * 1024 + l * 16) = v;
    }
}

// ---------------- fused MFMA match kernel v4 ----------------
// 512 thr = 8 waves: wm=w>>1 (32-row quadrant = 1 rowgroup), wn=w&1 (64-col half).
// A frags in VGPR (64/wave), B in 4x16KB LDS ring, counted vmcnt (never 0).
// Phases: P0 buf0=Bhi K0-63 x{aks0,aks2}; P1 buf1=Bhi K64-127 x{aks1,aks3};
//         P2 buf2=Blo K0-63 x{aks0};     P3 buf3=Blo K64-127 x{aks1}.

#define STAGE(BUF, J0V, C16B)                                                     \
    {                                                                             \
        _Pragma("unroll")                                                         \
        for (int c_ = 0; c_ < 2; ++c_) {                                          \
            int chunk_ = w * 2 + c_;                                              \
            int nf_ = chunk_ >> 2, c16_ = chunk_ & 3;                             \
            size_t gc_ = (size_t)(((J0V) >> 5) + nf_) * 16 + (C16B) + c16_;       \
            gload_lds16((const char*)B2c + gc_ * 1024 + l * 16,                   \
                        LDSB + (BUF) * 16384 + chunk_ * 1024 + l * 16);           \
        }                                                                         \
    }

#define COMP2(BUF, AKA, AKB)                                                      \
    {                                                                             \
        _Pragma("unroll")                                                         \
        for (int k16_ = 0; k16_ < 4; ++k16_) {                                    \
            f16x8 b0_ = *(const f16x8*)(LDSB + (BUF) * 16384 + ((wn * 2 + 0) * 4 + k16_) * 1024 + l * 16); \
            f16x8 b1_ = *(const f16x8*)(LDSB + (BUF) * 16384 + ((wn * 2 + 1) * 4 + k16_) * 1024 + l * 16); \
            acc[0] = mfma16(Areg[AKA][k16_], b0_, acc[0]);                        \
            acc[1] = mfma16(Areg[AKA][k16_], b1_, acc[1]);                        \
            acc[0] = mfma16(Areg[AKB][k16_], b0_, acc[0]);                        \
            acc[1] = mfma16(Areg[AKB][k16_], b1_, acc[1]);                        \
        }                                                                         \
    }

#define COMP1(BUF, AKA)                                                           \
    {                                                                             \
        _Pragma("unroll")                                                         \
        for (int k16_ = 0; k16_ < 4; ++k16_) {                                    \
            f16x8 b0_ = *(const f16x8*)(LDSB + (BUF) * 16384 + ((wn * 2 + 0) * 4 + k16_) * 1024 + l * 16); \
            f16x8 b1_ = *(const f16x8*)(LDSB + (BUF) * 16384 + ((wn * 2 + 1) * 4 + k16_) * 1024 + l * 16); \
            acc[0] = mfma16(Areg[AKA][k16_], b0_, acc[0]);                        \
            acc[1] = mfma16(Areg[AKA][k16_], b1_, acc[1]);                        \
        }                                                                         \
    }

#define PH(VM, STG, CMP)                                         \
    asm volatile("s_waitcnt vmcnt(" VM ")" ::: "memory");        \
    __builtin_amdgcn_s_barrier();                                \
    __builtin_amdgcn_sched_barrier(0);                           \
    STG;                                                         \
    __builtin_amdgcn_s_setprio(1);                               \
    CMP;                                                         \
    __builtin_amdgcn_s_setprio(0);

__global__ __launch_bounds__(512, 2) void match_kernel(
    const unsigned short* __restrict__ A2c, const unsigned short* __restrict__ B2c,
    const float* __restrict__ n1, const float* __restrict__ n2,
    float* __restrict__ pb, int* __restrict__ pj) {
    __shared__ __align__(16) char LDSB[4 * 16384];   // 64 KB ring
    __shared__ float LDSn1[128];
    const int t = threadIdx.x;
    const int l = t & 63, w = t >> 6;
    const int wm = w >> 1, wn = w & 1;
    const int c5 = l & 31, h = l >> 5;
    const int bi = blockIdx.x, ch = blockIdx.y;
    const int R0 = bi * MB;

    // A fragments -> registers (16 coalesced 1KB wave-loads; 64 VGPR)
    f16x8 Areg[4][4];
#pragma unroll
    for (int aks = 0; aks < 4; ++aks)
#pragma unroll
        for (int k16 = 0; k16 < 4; ++k16) {
            size_t g = (size_t)(bi * 4 + wm);
            Areg[aks][k16] = *(const f16x8*)(
                (const char*)A2c + (g * 16 + aks * 4 + k16) * 1024 + l * 16);
        }
    if (t < 128) LDSn1[t] = n1[R0 + t];

    const int jt0 = (ch * NJT) / NCHUNK;
    const int jt1 = ((ch + 1) * NJT) / NCHUNK;

    // prologue: 3 buffers in flight (6 loads)
    STAGE(0, jt0 * BN, 0);
    STAGE(1, jt0 * BN, 4);
    STAGE(2, jt0 * BN, 8);
    asm volatile("s_waitcnt lgkmcnt(0)" ::: "memory");   // LDSn1 committed

    float best[4];
    int bj[4];
#pragma unroll
    for (int rq = 0; rq < 4; ++rq) { best[rq] = 3.4e38f; bj[rq] = 0; }

    for (int jt = jt0; jt < jt1; ++jt) {
        const int j0 = jt * BN;
        float nn0 = n2[j0 + wn * 64 + c5];           // pinned here by PH clobbers
        float nn1 = n2[j0 + wn * 64 + 32 + c5];
        f32x16 acc[2];
#pragma unroll
        for (int b = 0; b < 2; ++b)
#pragma unroll
            for (int e = 0; e < 16; ++e) acc[b][e] = 0.f;

        PH("6", STAGE(3, j0, 12),      COMP2(0, 0, 2));   // P0
        PH("6", STAGE(0, j0 + BN, 0),  COMP2(1, 1, 3));   // P1
        PH("6", STAGE(1, j0 + BN, 4),  COMP1(2, 0));      // P2
        PH("4", STAGE(2, j0 + BN, 8),  COMP1(3, 1));      // P3 (tail stages land in slack)

        // epilogue: e_m = n1_m - 2*dot (dot = acc/4096); min over versions; + n2; argmin
#pragma unroll
        for (int b = 0; b < 2; ++b) {
            float nn = b ? nn1 : nn0;
            int j = j0 + wn * 64 + b * 32 + c5;
#pragma unroll
            for (int rq = 0; rq < 4; ++rq) {
                float4 n1v = *(const float4*)&LDSn1[wm * 32 + 8 * rq + 4 * h];
                float e0 = fmaf(-0.00048828125f, acc[b][4 * rq + 0], n1v.x);
                float e1 = fmaf(-0.00048828125f, acc[b][4 * rq + 1], n1v.y);
                float e2 = fmaf(-0.00048828125f, acc[b][4 * rq + 2], n1v.z);
                float e3 = fmaf(-0.00048828125f, acc[b][4 * rq + 3], n1v.w);
                float d = fminf(fminf(e0, e1), fminf(e2, e3)) + nn;
                if (d < best[rq]) { best[rq] = d; bj[rq] = j; }
            }
        }
    }

    // reduce across 32 column-lanes (xor offs < 32 keep h fixed)
#pragma unroll
    for (int off = 1; off < 32; off <<= 1) {
#pragma unroll
        for (int rq = 0; rq < 4; ++rq) {
            float ov = __shfl_xor(best[rq], off);
            int oj = __shfl_xor(bj[rq], off);
            if (ov < best[rq] || (ov == best[rq] && oj < bj[rq])) {
                best[rq] = ov; bj[rq] = oj;
            }
        }
    }
    if (c5 == 0) {
        int slot = ch * 2 + wn;
#pragma unroll
        for (int rq = 0; rq < 4; ++rq) {
            int i = bi * 32 + wm * 8 + 2 * rq + h;
            pb[slot * B1P + i] = best[rq];
            pj[slot * B1P + i] = bj[rq];
        }
    }
}

__global__ void final_kernel(const float* __restrict__ pb, const int* __restrict__ pj,
                             float* __restrict__ out) {
    int i = blockIdx.x * 256 + threadIdx.x;
    if (i < NB1) {
        float bv = 3.4e38f;
        int bj = 0;
#pragma unroll
        for (int s = 0; s < 2 * NCHUNK; ++s) {
            float v = pb[s * B1P + i];
            int j = pj[s * B1P + i];
            if (v < bv || (v == bv && j < bj)) { bv = v; bj = j; }
        }
        out[i] = sqrtf(fmaxf(bv, 0.f));
        out[NB1 + 2 * i] = (float)i;
        out[NB1 + 2 * i + 1] = (float)bj;
    }
}

// ---------------- launch ----------------

extern "C" void kernel_launch(void* const* d_in, const int* in_sizes, int n_in,
                              void* d_out, int out_size, void* d_ws, size_t ws_size,
                              hipStream_t stream) {
    const float* desc1 = (const float*)d_in[0];
    const float* desc2 = (const float*)d_in[1];
    const float* G     = (const float*)d_in[2];

    unsigned short* A2c = (unsigned short*)d_ws;                 // 1256*8192 ushort
    unsigned short* B2c = A2c + (size_t)(B1R / 32) * 8192;       // NB2G*8192 ushort
    float* GT = (float*)(B2c + (size_t)NB2G * 8192);             // DD*DD
    float* n1 = GT + DD * DD;                                    // B1R
    float* n2 = n1 + B1R;                                        // NB2P
    float* pb = n2 + NB2P;                                       // 2*NCHUNK*B1P
    int*   pj = (int*)(pb + 2 * NCHUNK * B1P);                   // 2*NCHUNK*B1P
    float* out = (float*)d_out;

    hipLaunchKernelGGL(gt_kernel, dim3((DD * DD + 255) / 256), dim3(256), 0, stream, G, GT);
    hipLaunchKernelGGL(prep1_kernel, dim3(B1P / 8), dim3(128), 0, stream,
                       desc1, GT, A2c, n1);
    hipLaunchKernelGGL(prep2_kernel, dim3(NB2P / 32), dim3(256), 0, stream,
                       desc2, B2c, n2);
    hipLaunchKernelGGL(match_kernel, dim3(B1R / MB, NCHUNK), dim3(512), 0, stream,
                       A2c, B2c, n1, n2, pb, pj);
    hipLaunchKernelGGL(final_kernel, dim3((NB1 + 255) / 256), dim3(256), 0, stream,
                       pb, pj, out);
}